// Round 3
// baseline (1647.096 us; speedup 1.0000x reference)
//
#include <hip/hip_runtime.h>
#include <math.h>

#define NFFT 1024
#define NF   513   // NFFT/2 + 1

__device__ __forceinline__ float2 cadd2(float2 a, float2 b){ return make_float2(a.x+b.x, a.y+b.y); }
__device__ __forceinline__ float2 csub2(float2 a, float2 b){ return make_float2(a.x-b.x, a.y-b.y); }
__device__ __forceinline__ float2 cmul2(float2 a, float2 b){ return make_float2(a.x*b.x - a.y*b.y, a.x*b.y + a.y*b.x); }

__device__ __forceinline__ float2 shflxor2(float2 v, int m){
    return make_float2(__shfl_xor(v.x, m), __shfl_xor(v.y, m));
}
__device__ __forceinline__ float2 shflidx2(float2 v, int idx){
    return make_float2(__shfl(v.x, idx), __shfl(v.y, idx));
}
__device__ __forceinline__ int brev6(int x){ return (int)(__brev((unsigned)x) >> 26); }

// ---- DPP wave reductions (VALU pipe, no DS ops). Result valid in lane 63. ----
__device__ __forceinline__ float dpp_sum63(float x){
    int v;
    v = __builtin_amdgcn_update_dpp(0, __float_as_int(x), 0x111, 0xf, 0xf, true); x += __int_as_float(v);
    v = __builtin_amdgcn_update_dpp(0, __float_as_int(x), 0x112, 0xf, 0xf, true); x += __int_as_float(v);
    v = __builtin_amdgcn_update_dpp(0, __float_as_int(x), 0x114, 0xf, 0xf, true); x += __int_as_float(v);
    v = __builtin_amdgcn_update_dpp(0, __float_as_int(x), 0x118, 0xf, 0xf, true); x += __int_as_float(v);
    v = __builtin_amdgcn_update_dpp(0, __float_as_int(x), 0x142, 0xa, 0xf, true); x += __int_as_float(v);
    v = __builtin_amdgcn_update_dpp(0, __float_as_int(x), 0x143, 0xc, 0xf, true); x += __int_as_float(v);
    return x;
}
__device__ __forceinline__ float dpp_max63(float x){   // operands >= 0 (0-fill safe)
    int v;
    v = __builtin_amdgcn_update_dpp(0, __float_as_int(x), 0x111, 0xf, 0xf, true); x = fmaxf(x, __int_as_float(v));
    v = __builtin_amdgcn_update_dpp(0, __float_as_int(x), 0x112, 0xf, 0xf, true); x = fmaxf(x, __int_as_float(v));
    v = __builtin_amdgcn_update_dpp(0, __float_as_int(x), 0x114, 0xf, 0xf, true); x = fmaxf(x, __int_as_float(v));
    v = __builtin_amdgcn_update_dpp(0, __float_as_int(x), 0x118, 0xf, 0xf, true); x = fmaxf(x, __int_as_float(v));
    v = __builtin_amdgcn_update_dpp(0, __float_as_int(x), 0x142, 0xa, 0xf, true); x = fmaxf(x, __int_as_float(v));
    v = __builtin_amdgcn_update_dpp(0, __float_as_int(x), 0x143, 0xc, 0xf, true); x = fmaxf(x, __int_as_float(v));
    return x;
}
__device__ __forceinline__ unsigned dpp_umax63(unsigned x){   // 0-fill safe for unsigned max
    int v; unsigned y;
    v = __builtin_amdgcn_update_dpp(0, (int)x, 0x111, 0xf, 0xf, true); y = (unsigned)v; x = x > y ? x : y;
    v = __builtin_amdgcn_update_dpp(0, (int)x, 0x112, 0xf, 0xf, true); y = (unsigned)v; x = x > y ? x : y;
    v = __builtin_amdgcn_update_dpp(0, (int)x, 0x114, 0xf, 0xf, true); y = (unsigned)v; x = x > y ? x : y;
    v = __builtin_amdgcn_update_dpp(0, (int)x, 0x118, 0xf, 0xf, true); y = (unsigned)v; x = x > y ? x : y;
    v = __builtin_amdgcn_update_dpp(0, (int)x, 0x142, 0xa, 0xf, true); y = (unsigned)v; x = x > y ? x : y;
    v = __builtin_amdgcn_update_dpp(0, (int)x, 0x143, 0xc, 0xf, true); y = (unsigned)v; x = x > y ? x : y;
    return x;
}
__device__ __forceinline__ float bcast63f(float x){
    return __int_as_float(__builtin_amdgcn_readlane(__float_as_int(x), 63));
}
__device__ __forceinline__ unsigned bcast63u(unsigned x){
    return (unsigned)__builtin_amdgcn_readlane((int)x, 63);
}

// exp(-i*pi*r/512), r = 0..7 (compile-time literals after unroll)
__device__ __forceinline__ float2 rotc(int r){
    const float C[8] = {1.0f, 0.99998117528f, 0.99992470184f, 0.99983058180f,
                        0.99969881870f, 0.99952941750f, 0.99932238459f, 0.99907772775f};
    const float S[8] = {0.0f, 0.00613588465f, 0.01227153829f, 0.01840672991f,
                        0.02454122852f, 0.03067480318f, 0.03680722294f, 0.04293825693f};
    return make_float2(C[r], -S[r]);
}

__device__ __forceinline__ float psd_combine(float2 z, float2 zr, float2 uw){
    float Ex = 0.5f * (z.x + zr.x);
    float Ey = 0.5f * (z.y - zr.y);
    float Ox = 0.5f * (z.y + zr.y);
    float Oy = -0.5f * (z.x - zr.x);
    float Xx = Ex + uw.x * Ox - uw.y * Oy;
    float Xy = Ey + uw.x * Oy + uw.y * Ox;
    return Xx * Xx + Xy * Xy;
}

// ---------------- Kernel 1: wave-per-row register FFT + PSD + stats ----------------
__global__ __launch_bounds__(256, 8)
void k1(const float* __restrict__ preds, const int* __restrict__ FsPtr,
        float* __restrict__ gpsd, float* __restrict__ gband, float* __restrict__ gsparse,
        int B, int rpw)
{
    const int tid  = threadIdx.x;
    const int lane = tid & 63;
    const int wid  = tid >> 6;
    const int Fs   = *FsPtr;

    // band parameters (uniform grid => argmin == rint(target/step))
    const double stepd = (double)Fs * 0.5 / (double)(NF - 1);
    const int left  = (int)rint((40.0 / 60.0) / stepd);
    const int right = (int)rint((180.0 / 60.0) / stepd);
    const double binw = (double)Fs * 0.5 / (double)NF;
    int delta = (int)rint((6.0 / 60.0) / binw);
    if (delta < 1) delta = 1;

    const int K  = brev6(lane);     // bin group after cross-lane DIF
    const int kk = K << 3;          // first output bin held by this lane
    const float PIF = 3.14159265358979323846f;

    // base twiddles (3 complex regs; everything else derived per row)
    float2 t512, w64, uw0;
    {
        float s, c;
        sincosf(-2.0f * PIF * (float)lane / 512.0f, &s, &c); t512 = make_float2(c, s);
        sincosf(-2.0f * PIF * (float)lane / 64.0f,  &s, &c); w64  = make_float2(c, s);
        sincosf(-PIF * (float)K / 64.0f,            &s, &c); uw0  = make_float2(c, s);
    }
    const int p0idx = brev6((64 - K) & 63);   // partner lane for reg 0

    float baccR[8] = {0.f,0.f,0.f,0.f,0.f,0.f,0.f,0.f};
    float bacc512 = 0.f;
    float accB = 0.f, accS = 0.f;

    const int gw   = blockIdx.x * 4 + wid;
    const int row0 = gw * rpw;

    for (int rr = 0; rr < rpw; ++rr) {
        const int row = row0 + rr;
        if (row >= B) break;

        // load row: z[r] = complex sample n = 64*r + lane (coalesced 8B/lane)
        const float2* src = (const float2*)(preds + (size_t)row * NFFT);
        float2 z[8];
        #pragma unroll
        for (int r = 0; r < 8; ++r) z[r] = src[(r << 6) + lane];

        // ---- step 1: 8-point DIT FFT in registers ----
        float2 c0 = cadd2(z[0], z[4]), c1 = csub2(z[0], z[4]);
        float2 c2 = cadd2(z[2], z[6]), c3 = csub2(z[2], z[6]);
        float2 c4 = cadd2(z[1], z[5]), c5 = csub2(z[1], z[5]);
        float2 c6 = cadd2(z[3], z[7]), c7 = csub2(z[3], z[7]);
        float2 mi3 = make_float2(c3.y, -c3.x);
        float2 mi7 = make_float2(c7.y, -c7.x);
        float2 d0 = cadd2(c0, c2), d2 = csub2(c0, c2);
        float2 d1 = cadd2(c1, mi3), d3 = csub2(c1, mi3);
        float2 d4 = cadd2(c4, c6), d6 = csub2(c4, c6);
        float2 d5 = cadd2(c5, mi7), d7 = csub2(c5, mi7);
        const float S2 = 0.70710678118654752f;
        float2 w1d5 = make_float2(S2 * (d5.x + d5.y), S2 * (d5.y - d5.x));
        float2 mid6 = make_float2(d6.y, -d6.x);
        float2 w3d7 = make_float2(S2 * (d7.y - d7.x), -S2 * (d7.x + d7.y));
        z[0] = cadd2(d0, d4);  z[4] = csub2(d0, d4);
        z[1] = cadd2(d1, w1d5); z[5] = csub2(d1, w1d5);
        z[2] = cadd2(d2, mid6); z[6] = csub2(d2, mid6);
        z[3] = cadd2(d3, w3d7); z[7] = csub2(d3, w3d7);

        // ---- step 2: twiddle W_512^{lane*r} via cmul chain ----
        {
            float2 w = t512;
            z[1] = cmul2(z[1], w);
            #pragma unroll
            for (int r = 2; r < 8; ++r) { w = cmul2(w, t512); z[r] = cmul2(z[r], w); }
        }

        // ---- step 3: 64-point DIF across lanes; stage twiddle derived by squaring ----
        {
            float2 v = w64;   // v_s = W64^{lane * 2^s}
            #pragma unroll
            for (int s = 0; s < 6; ++s) {
                const int m = 32 >> s;
                const bool hi = (lane & m) != 0;
                #pragma unroll
                for (int r = 0; r < 8; ++r) {
                    float2 p = shflxor2(z[r], m);
                    float2 a = cadd2(z[r], p);
                    float2 b = cmul2(csub2(z[r], p), v);   // == (p - z)*wS on hi lanes
                    z[r] = hi ? b : a;
                }
                v = cmul2(v, v);
            }
        }
        // lane holds Z[kk + r]

        float p512 = 0.f;
        if (lane == 0) { float q = z[0].x - z[0].y; p512 = q * q; }

        // ---- real-unpack + PSD in registers ----
        float P[8];
        {
            float2 zr = shflidx2(z[0], p0idx);
            P[0] = psd_combine(z[0], zr, uw0);
        }
        #pragma unroll
        for (int r = 1; r < 8; ++r) {
            float2 zr = shflxor2(z[8 - r], 63);
            float2 uwr = cmul2(uw0, rotc(r));
            P[r] = psd_combine(z[r], zr, uwr);
        }

        // ---- stats: DPP reductions (no DS ops) ----
        float tp = p512, ip = 0.f, mv = 0.f;
        #pragma unroll
        for (int r = 0; r < 8; ++r) {
            const int k = kk + r;
            tp += P[r];
            if (k >= left && k < right) { ip += P[r]; mv = fmaxf(mv, P[r]); }
        }
        const float tpS = dpp_sum63(tp);
        const float ipS = dpp_sum63(ip);
        const float mx  = bcast63f(dpp_max63(mv));

        unsigned cand = 0u;
        #pragma unroll
        for (int r = 0; r < 8; ++r) {
            const int k = kk + r;
            if (k >= left && k < right && P[r] == mx) {
                unsigned c = ~(unsigned)k;
                cand = cand > c ? cand : c;
            }
        }
        const int peak = (int)(~bcast63u(dpp_umax63(cand)));
        const int lo  = max(left, peak - delta);
        const int hi2 = min(right, peak + delta);
        float ns = 0.f;
        #pragma unroll
        for (int r = 0; r < 8; ++r) { const int k = kk + r; if (k >= lo && k < hi2) ns += P[r]; }
        const float nsS = dpp_sum63(ns);

        accB += (tpS - ipS) / (1e-8f + tpS);
        accS += (ipS - nsS) / (ipS + 1e-8f * (float)(right - left));

        #pragma unroll
        for (int r = 0; r < 8; ++r) baccR[r] += P[r];
        bacc512 += p512;
    }

    // ---- per-wave flush straight to global atomics (no LDS, no barriers) ----
    #pragma unroll
    for (int r = 0; r < 8; ++r) atomicAdd(&gpsd[kk + r], baccR[r]);
    if (lane == 0)  atomicAdd(&gpsd[512], bacc512);
    if (lane == 63) { atomicAdd(gband, accB); atomicAdd(gsparse, accS); }
}

// ---------------- Kernel 2: variance loss + final combine ----------------
__global__ __launch_bounds__(256)
void k2(const float* __restrict__ gpsd, const float* __restrict__ gband,
        const float* __restrict__ gsparse, const int* __restrict__ FsPtr,
        float* __restrict__ out, int B)
{
    __shared__ float a[NF];
    __shared__ float b[NF];
    __shared__ float red[4];

    const int tid = threadIdx.x;
    const int Fs  = *FsPtr;

    a[tid] = gpsd[tid]; a[tid + 256] = gpsd[tid + 256];
    if (tid == 0) a[512] = gpsd[512];
    __syncthreads();

    float sp = a[tid] + a[tid + 256] + (tid == 0 ? a[512] : 0.f);
    #pragma unroll
    for (int off = 32; off > 0; off >>= 1) sp += __shfl_down(sp, off);
    const int wid = tid >> 6, lane = tid & 63;
    if (lane == 0) red[wid] = sp;
    __syncthreads();
    const float S = red[0] + red[1] + red[2] + red[3];
    const float inv = 1.f / (1e-8f + S);
    a[tid] *= inv; a[tid + 256] *= inv;
    if (tid == 0) a[512] *= inv;
    __syncthreads();

    float* pa = a; float* pb = b;
    for (int off = 1; off < NF; off <<= 1) {
        for (int i = tid; i < NF; i += 256)
            pb[i] = pa[i] + (i >= off ? pa[i - off] : 0.f);
        __syncthreads();
        float* t = pa; pa = pb; pb = t;
    }

    const double fs2 = (double)Fs * 0.5;
    const double stp = fs2 / (double)(NF - 1);
    float vp = 0.f;
    for (int i = tid; i < NF; i += 256) {
        float Q = fminf(fmaxf(pa[i], 0.f), 1.f);
        float P = (float)((double)i * stp) / (float)fs2;
        P = fminf(fmaxf(P, 0.f), 1.f);
        const float d = P - Q;
        vp += d * d;
    }
    #pragma unroll
    for (int off = 32; off > 0; off >>= 1) vp += __shfl_down(vp, off);
    if (lane == 0) red[wid] = vp;
    __syncthreads();
    if (tid == 0) {
        const float var = (red[0] + red[1] + red[2] + red[3]) / (float)NF;
        out[0] = (*gband) / (float)B + (*gsparse) / (float)B + var;
    }
}

extern "C" void kernel_launch(void* const* d_in, const int* in_sizes, int n_in,
                              void* d_out, int out_size, void* d_ws, size_t ws_size,
                              hipStream_t stream)
{
    const float* preds = (const float*)d_in[0];
    const int*   Fs    = (const int*)d_in[1];
    const int B = in_sizes[0] / NFFT;

    float* gpsd    = (float*)d_ws;
    float* gband   = gpsd + NF;
    float* gsparse = gband + 1;

    hipMemsetAsync(d_ws, 0, (NF + 2) * sizeof(float), stream);

    const int rpw    = 2;
    const int nwaves = (B + rpw - 1) / rpw;
    const int nblk   = (nwaves + 3) / 4;

    hipLaunchKernelGGL(k1, dim3(nblk), dim3(256), 0, stream,
                       preds, Fs, gpsd, gband, gsparse, B, rpw);
    hipLaunchKernelGGL(k2, dim3(1), dim3(256), 0, stream,
                       gpsd, gband, gsparse, Fs, (float*)d_out, B);
}

// Round 5
// 838.442 us; speedup vs baseline: 1.9645x; 1.9645x over previous
//
#include <hip/hip_runtime.h>
#include <math.h>

#define NFFT 1024
#define NF   513   // NFFT/2 + 1

__device__ __forceinline__ float2 cadd2(float2 a, float2 b){ return make_float2(a.x+b.x, a.y+b.y); }
__device__ __forceinline__ float2 csub2(float2 a, float2 b){ return make_float2(a.x-b.x, a.y-b.y); }
__device__ __forceinline__ float2 cmul2(float2 a, float2 b){ return make_float2(a.x*b.x - a.y*b.y, a.x*b.y + a.y*b.x); }

__device__ __forceinline__ float2 shflxor2(float2 v, int m){
    return make_float2(__shfl_xor(v.x, m), __shfl_xor(v.y, m));
}
__device__ __forceinline__ float2 shflidx2(float2 v, int idx){
    return make_float2(__shfl(v.x, idx), __shfl(v.y, idx));
}
__device__ __forceinline__ int brev6(int x){ return (int)(__brev((unsigned)x) >> 26); }

// DPP quad_perm: xor1 = [1,0,3,2] = 0xB1, xor2 = [2,3,0,1] = 0x4E
template<int CTRL>
__device__ __forceinline__ float2 dppqp2(float2 v){
    int x = __builtin_amdgcn_update_dpp(0, __float_as_int(v.x), CTRL, 0xf, 0xf, true);
    int y = __builtin_amdgcn_update_dpp(0, __float_as_int(v.y), CTRL, 0xf, 0xf, true);
    return make_float2(__int_as_float(x), __int_as_float(y));
}

// ---- DPP wave reductions (VALU pipe). Result valid in lane 63. ----
__device__ __forceinline__ float dpp_sum63(float x){
    int v;
    v = __builtin_amdgcn_update_dpp(0, __float_as_int(x), 0x111, 0xf, 0xf, true); x += __int_as_float(v);
    v = __builtin_amdgcn_update_dpp(0, __float_as_int(x), 0x112, 0xf, 0xf, true); x += __int_as_float(v);
    v = __builtin_amdgcn_update_dpp(0, __float_as_int(x), 0x114, 0xf, 0xf, true); x += __int_as_float(v);
    v = __builtin_amdgcn_update_dpp(0, __float_as_int(x), 0x118, 0xf, 0xf, true); x += __int_as_float(v);
    v = __builtin_amdgcn_update_dpp(0, __float_as_int(x), 0x142, 0xa, 0xf, true); x += __int_as_float(v);
    v = __builtin_amdgcn_update_dpp(0, __float_as_int(x), 0x143, 0xc, 0xf, true); x += __int_as_float(v);
    return x;
}
__device__ __forceinline__ float dpp_max63(float x){   // operands >= 0
    int v;
    v = __builtin_amdgcn_update_dpp(0, __float_as_int(x), 0x111, 0xf, 0xf, true); x = fmaxf(x, __int_as_float(v));
    v = __builtin_amdgcn_update_dpp(0, __float_as_int(x), 0x112, 0xf, 0xf, true); x = fmaxf(x, __int_as_float(v));
    v = __builtin_amdgcn_update_dpp(0, __float_as_int(x), 0x114, 0xf, 0xf, true); x = fmaxf(x, __int_as_float(v));
    v = __builtin_amdgcn_update_dpp(0, __float_as_int(x), 0x118, 0xf, 0xf, true); x = fmaxf(x, __int_as_float(v));
    v = __builtin_amdgcn_update_dpp(0, __float_as_int(x), 0x142, 0xa, 0xf, true); x = fmaxf(x, __int_as_float(v));
    v = __builtin_amdgcn_update_dpp(0, __float_as_int(x), 0x143, 0xc, 0xf, true); x = fmaxf(x, __int_as_float(v));
    return x;
}
__device__ __forceinline__ unsigned dpp_umax63(unsigned x){
    int v; unsigned y;
    v = __builtin_amdgcn_update_dpp(0, (int)x, 0x111, 0xf, 0xf, true); y = (unsigned)v; x = x > y ? x : y;
    v = __builtin_amdgcn_update_dpp(0, (int)x, 0x112, 0xf, 0xf, true); y = (unsigned)v; x = x > y ? x : y;
    v = __builtin_amdgcn_update_dpp(0, (int)x, 0x114, 0xf, 0xf, true); y = (unsigned)v; x = x > y ? x : y;
    v = __builtin_amdgcn_update_dpp(0, (int)x, 0x118, 0xf, 0xf, true); y = (unsigned)v; x = x > y ? x : y;
    v = __builtin_amdgcn_update_dpp(0, (int)x, 0x142, 0xa, 0xf, true); y = (unsigned)v; x = x > y ? x : y;
    v = __builtin_amdgcn_update_dpp(0, (int)x, 0x143, 0xc, 0xf, true); y = (unsigned)v; x = x > y ? x : y;
    return x;
}
__device__ __forceinline__ float bcast63f(float x){
    return __int_as_float(__builtin_amdgcn_readlane(__float_as_int(x), 63));
}
__device__ __forceinline__ unsigned bcast63u(unsigned x){
    return (unsigned)__builtin_amdgcn_readlane((int)x, 63);
}

// exp(-i*pi*r/512), r = 0..7 (compile-time literals after unroll)
__device__ __forceinline__ float2 rotc(int r){
    const float C[8] = {1.0f, 0.99998117528f, 0.99992470184f, 0.99983058180f,
                        0.99969881870f, 0.99952941750f, 0.99932238459f, 0.99907772775f};
    const float S[8] = {0.0f, 0.00613588465f, 0.01227153829f, 0.01840672991f,
                        0.02454122852f, 0.03067480318f, 0.03680722294f, 0.04293825693f};
    return make_float2(C[r], -S[r]);
}

__device__ __forceinline__ float psd_combine(float2 z, float2 zr, float2 uw){
    float Ex = 0.5f * (z.x + zr.x);
    float Ey = 0.5f * (z.y - zr.y);
    float Ox = 0.5f * (z.y + zr.y);
    float Oy = -0.5f * (z.x - zr.x);
    float Xx = Ex + uw.x * Ox - uw.y * Oy;
    float Xy = Ey + uw.x * Oy + uw.y * Ox;
    return Xx * Xx + Xy * Xy;
}

// 8-point DIT FFT in registers, natural-order output
__device__ __forceinline__ void fft8(float2* z){
    float2 c0 = cadd2(z[0], z[4]), c1 = csub2(z[0], z[4]);
    float2 c2 = cadd2(z[2], z[6]), c3 = csub2(z[2], z[6]);
    float2 c4 = cadd2(z[1], z[5]), c5 = csub2(z[1], z[5]);
    float2 c6 = cadd2(z[3], z[7]), c7 = csub2(z[3], z[7]);
    float2 mi3 = make_float2(c3.y, -c3.x);
    float2 mi7 = make_float2(c7.y, -c7.x);
    float2 d0 = cadd2(c0, c2), d2 = csub2(c0, c2);
    float2 d1 = cadd2(c1, mi3), d3 = csub2(c1, mi3);
    float2 d4 = cadd2(c4, c6), d6 = csub2(c4, c6);
    float2 d5 = cadd2(c5, mi7), d7 = csub2(c5, mi7);
    const float S2 = 0.70710678118654752f;
    float2 w1d5 = make_float2(S2 * (d5.x + d5.y), S2 * (d5.y - d5.x));
    float2 mid6 = make_float2(d6.y, -d6.x);
    float2 w3d7 = make_float2(S2 * (d7.y - d7.x), -S2 * (d7.x + d7.y));
    z[0] = cadd2(d0, d4);  z[4] = csub2(d0, d4);
    z[1] = cadd2(d1, w1d5); z[5] = csub2(d1, w1d5);
    z[2] = cadd2(d2, mid6); z[6] = csub2(d2, mid6);
    z[3] = cadd2(d3, w3d7); z[7] = csub2(d3, w3d7);
}

// ---------------- Kernel 1: wave-per-2-rows register FFT + PSD + stats ----------------
__global__ __launch_bounds__(256, 4)
void k1(const float* __restrict__ preds, const int* __restrict__ FsPtr,
        float* __restrict__ gpsd, float* __restrict__ gband, float* __restrict__ gsparse,
        int B, int npair)
{
    const int tid  = threadIdx.x;
    const int lane = tid & 63;
    const int wid  = tid >> 6;
    const int Fs   = *FsPtr;

    // band parameters (uniform grid => argmin == rint(target/step))
    const double stepd = (double)Fs * 0.5 / (double)(NF - 1);
    const int left  = (int)rint((40.0 / 60.0) / stepd);
    const int right = (int)rint((180.0 / 60.0) / stepd);
    const double binw = (double)Fs * 0.5 / (double)NF;
    int delta = (int)rint((6.0 / 60.0) / binw);
    if (delta < 1) delta = 1;

    const int K  = brev6(lane);
    const int kk = K << 3;
    const float PIF = 3.14159265358979323846f;

    // twiddle tables (registers)
    float2 tw2[8];                        // W_512^{lane*r}, r=1..7
    #pragma unroll
    for (int r = 1; r < 8; ++r) {
        float s, c;
        sincosf(-2.0f * PIF * (float)(lane * r) / 512.0f, &s, &c);
        tw2[r] = make_float2(c, s);
    }
    float2 wS[6];                         // hi lanes: W_{2m}^{lane&(m-1)}, lo: (1,0)
    #pragma unroll
    for (int s = 0; s < 6; ++s) {
        const int m = 32 >> s;
        if (lane & m) {
            float sn, cs;
            sincosf(-2.0f * PIF * (float)(lane & (m - 1)) / (float)(2 * m), &sn, &cs);
            wS[s] = make_float2(cs, sn);
        } else {
            wS[s] = make_float2(1.f, 0.f);
        }
    }
    float2 uw0;
    { float s, c; sincosf(-PIF * (float)K / 64.0f, &s, &c); uw0 = make_float2(c, s); }
    const int p0idx = brev6((64 - K) & 63);

    float baccR[8] = {0.f,0.f,0.f,0.f,0.f,0.f,0.f,0.f};
    float bacc512 = 0.f;
    float accB = 0.f, accS = 0.f;

    const int gw   = blockIdx.x * 4 + wid;
    const int row0base = gw * (2 * npair);

    for (int pp = 0; pp < npair; ++pp) {
        const int rowA = row0base + 2 * pp;
        if (rowA >= B) break;
        const int rowB = rowA + 1;
        const float valB = (rowB < B) ? 1.f : 0.f;
        const int rowBc = (rowB < B) ? rowB : rowA;

        // ---- load both rows (coalesced 8B/lane) ----
        const float2* srcA = (const float2*)(preds + (size_t)rowA * NFFT);
        const float2* srcB = (const float2*)(preds + (size_t)rowBc * NFFT);
        float2 zA[8], zB[8];
        #pragma unroll
        for (int r = 0; r < 8; ++r) { zA[r] = srcA[(r << 6) + lane]; zB[r] = srcB[(r << 6) + lane]; }

        // ---- step 1: 8-point FFT (both rows) ----
        fft8(zA);
        fft8(zB);

        // ---- step 2: twiddle W_512^{lane*r} ----
        #pragma unroll
        for (int r = 1; r < 8; ++r) { zA[r] = cmul2(zA[r], tw2[r]); zB[r] = cmul2(zB[r], tw2[r]); }

        // ---- step 3: 64-point DIF across lanes, both rows interleaved ----
        #pragma unroll
        for (int s = 0; s < 6; ++s) {
            const int m = 32 >> s;
            const float sg = (lane & m) ? -1.f : 1.f;
            const float2 w = wS[s];
            #pragma unroll
            for (int r = 0; r < 8; ++r) {
                float2 pA, pB;
                if (m >= 4)      { pA = shflxor2(zA[r], m);    pB = shflxor2(zB[r], m); }
                else if (m == 2) { pA = dppqp2<0x4E>(zA[r]);   pB = dppqp2<0x4E>(zB[r]); }
                else             { pA = dppqp2<0xB1>(zA[r]);   pB = dppqp2<0xB1>(zB[r]); }
                // lo: (z+p)*1 ; hi: (p-z)*wS  -> inner = p + sg*z, then *w
                float2 iA = make_float2(fmaf(sg, zA[r].x, pA.x), fmaf(sg, zA[r].y, pA.y));
                float2 iB = make_float2(fmaf(sg, zB[r].x, pB.x), fmaf(sg, zB[r].y, pB.y));
                zA[r] = cmul2(iA, w);
                zB[r] = cmul2(iB, w);
            }
        }
        // lane holds Z[kk + r] for each row

        float p512A = 0.f, p512B = 0.f;
        if (lane == 0) {
            float qA = zA[0].x - zA[0].y; p512A = qA * qA;
            float qB = zB[0].x - zB[0].y; p512B = qB * qB;
        }

        // ---- real-unpack + PSD (both rows) ----
        float PA[8], PB[8];
        {
            float2 zrA = shflidx2(zA[0], p0idx);
            float2 zrB = shflidx2(zB[0], p0idx);
            PA[0] = psd_combine(zA[0], zrA, uw0);
            PB[0] = psd_combine(zB[0], zrB, uw0);
        }
        #pragma unroll
        for (int r = 1; r < 8; ++r) {
            float2 uwr = cmul2(uw0, rotc(r));
            float2 zrA = shflxor2(zA[8 - r], 63);
            float2 zrB = shflxor2(zB[8 - r], 63);
            PA[r] = psd_combine(zA[r], zrA, uwr);
            PB[r] = psd_combine(zB[r], zrB, uwr);
        }

        // ---- stats (both rows, DPP reductions) ----
        float tpA = p512A, ipA = 0.f, mvA = 0.f;
        float tpB = p512B, ipB = 0.f, mvB = 0.f;
        #pragma unroll
        for (int r = 0; r < 8; ++r) {
            const int k = kk + r;
            tpA += PA[r]; tpB += PB[r];
            if (k >= left && k < right) {
                ipA += PA[r]; mvA = fmaxf(mvA, PA[r]);
                ipB += PB[r]; mvB = fmaxf(mvB, PB[r]);
            }
        }
        const float tpSA = dpp_sum63(tpA), tpSB = dpp_sum63(tpB);
        const float ipSA = dpp_sum63(ipA), ipSB = dpp_sum63(ipB);
        const float mxA = bcast63f(dpp_max63(mvA));
        const float mxB = bcast63f(dpp_max63(mvB));

        unsigned candA = 0u, candB = 0u;
        #pragma unroll
        for (int r = 0; r < 8; ++r) {
            const int k = kk + r;
            if (k >= left && k < right) {
                if (PA[r] == mxA) { unsigned c = ~(unsigned)k; candA = candA > c ? candA : c; }
                if (PB[r] == mxB) { unsigned c = ~(unsigned)k; candB = candB > c ? candB : c; }
            }
        }
        const int peakA = (int)(~bcast63u(dpp_umax63(candA)));
        const int peakB = (int)(~bcast63u(dpp_umax63(candB)));
        const int loA = max(left, peakA - delta), hiA = min(right, peakA + delta);
        const int loB = max(left, peakB - delta), hiB = min(right, peakB + delta);
        float nsA = 0.f, nsB = 0.f;
        #pragma unroll
        for (int r = 0; r < 8; ++r) {
            const int k = kk + r;
            if (k >= loA && k < hiA) nsA += PA[r];
            if (k >= loB && k < hiB) nsB += PB[r];
        }
        const float nsSA = dpp_sum63(nsA), nsSB = dpp_sum63(nsB);

        const float eps = 1e-8f * (float)(right - left);
        accB += (tpSA - ipSA) / (1e-8f + tpSA) + valB * ((tpSB - ipSB) / (1e-8f + tpSB));
        accS += (ipSA - nsSA) / (ipSA + eps)   + valB * ((ipSB - nsSB) / (ipSB + eps));

        #pragma unroll
        for (int r = 0; r < 8; ++r) baccR[r] += PA[r] + valB * PB[r];
        bacc512 += p512A + valB * p512B;
    }

    // ---- per-wave flush straight to global atomics ----
    #pragma unroll
    for (int r = 0; r < 8; ++r) atomicAdd(&gpsd[kk + r], baccR[r]);
    if (lane == 0)  atomicAdd(&gpsd[512], bacc512);
    if (lane == 63) { atomicAdd(gband, accB); atomicAdd(gsparse, accS); }
}

// ---------------- Kernel 2: variance loss + final combine ----------------
__global__ __launch_bounds__(256)
void k2(const float* __restrict__ gpsd, const float* __restrict__ gband,
        const float* __restrict__ gsparse, const int* __restrict__ FsPtr,
        float* __restrict__ out, int B)
{
    __shared__ float a[NF];
    __shared__ float b[NF];
    __shared__ float red[4];

    const int tid = threadIdx.x;
    const int Fs  = *FsPtr;

    a[tid] = gpsd[tid]; a[tid + 256] = gpsd[tid + 256];
    if (tid == 0) a[512] = gpsd[512];
    __syncthreads();

    float sp = a[tid] + a[tid + 256] + (tid == 0 ? a[512] : 0.f);
    #pragma unroll
    for (int off = 32; off > 0; off >>= 1) sp += __shfl_down(sp, off);
    const int wid = tid >> 6, lane = tid & 63;
    if (lane == 0) red[wid] = sp;
    __syncthreads();
    const float S = red[0] + red[1] + red[2] + red[3];
    const float inv = 1.f / (1e-8f + S);
    a[tid] *= inv; a[tid + 256] *= inv;
    if (tid == 0) a[512] *= inv;
    __syncthreads();

    float* pa = a; float* pb = b;
    for (int off = 1; off < NF; off <<= 1) {
        for (int i = tid; i < NF; i += 256)
            pb[i] = pa[i] + (i >= off ? pa[i - off] : 0.f);
        __syncthreads();
        float* t = pa; pa = pb; pb = t;
    }

    const double fs2 = (double)Fs * 0.5;
    const double stp = fs2 / (double)(NF - 1);
    float vp = 0.f;
    for (int i = tid; i < NF; i += 256) {
        float Q = fminf(fmaxf(pa[i], 0.f), 1.f);
        float P = (float)((double)i * stp) / (float)fs2;
        P = fminf(fmaxf(P, 0.f), 1.f);
        const float d = P - Q;
        vp += d * d;
    }
    #pragma unroll
    for (int off = 32; off > 0; off >>= 1) vp += __shfl_down(vp, off);
    if (lane == 0) red[wid] = vp;
    __syncthreads();
    if (tid == 0) {
        const float var = (red[0] + red[1] + red[2] + red[3]) / (float)NF;
        out[0] = (*gband) / (float)B + (*gsparse) / (float)B + var;
    }
}

extern "C" void kernel_launch(void* const* d_in, const int* in_sizes, int n_in,
                              void* d_out, int out_size, void* d_ws, size_t ws_size,
                              hipStream_t stream)
{
    const float* preds = (const float*)d_in[0];
    const int*   Fs    = (const int*)d_in[1];
    const int B = in_sizes[0] / NFFT;

    float* gpsd    = (float*)d_ws;
    float* gband   = gpsd + NF;
    float* gsparse = gband + 1;

    (void)hipMemsetAsync(d_ws, 0, (NF + 2) * sizeof(float), stream);

    const int npair = 2;                      // 4 rows per wave
    const int rowsPerWave = 2 * npair;
    const int nwaves = (B + rowsPerWave - 1) / rowsPerWave;
    const int nblk   = (nwaves + 3) / 4;

    hipLaunchKernelGGL(k1, dim3(nblk), dim3(256), 0, stream,
                       preds, Fs, gpsd, gband, gsparse, B, npair);
    hipLaunchKernelGGL(k2, dim3(1), dim3(256), 0, stream,
                       gpsd, gband, gsparse, Fs, (float*)d_out, B);
}

// Round 6
// 817.303 us; speedup vs baseline: 2.0153x; 1.0259x over previous
//
#include <hip/hip_runtime.h>
#include <math.h>

#define NFFT 1024
#define NF   513   // NFFT/2 + 1

__device__ __forceinline__ float2 cadd2(float2 a, float2 b){ return make_float2(a.x+b.x, a.y+b.y); }
__device__ __forceinline__ float2 csub2(float2 a, float2 b){ return make_float2(a.x-b.x, a.y-b.y); }
__device__ __forceinline__ float2 cmul2(float2 a, float2 b){ return make_float2(a.x*b.x - a.y*b.y, a.x*b.y + a.y*b.x); }

__device__ __forceinline__ float2 shflxor2(float2 v, int m){
    return make_float2(__shfl_xor(v.x, m), __shfl_xor(v.y, m));
}
__device__ __forceinline__ float2 shflidx2(float2 v, int idx){
    return make_float2(__shfl(v.x, idx), __shfl(v.y, idx));
}
__device__ __forceinline__ int brev6(int x){ return (int)(__brev((unsigned)x) >> 26); }

// DPP quad_perm: xor1 = [1,0,3,2] = 0xB1, xor2 = [2,3,0,1] = 0x4E
template<int CTRL>
__device__ __forceinline__ float2 dppqp2(float2 v){
    int x = __builtin_amdgcn_update_dpp(0, __float_as_int(v.x), CTRL, 0xf, 0xf, true);
    int y = __builtin_amdgcn_update_dpp(0, __float_as_int(v.y), CTRL, 0xf, 0xf, true);
    return make_float2(__int_as_float(x), __int_as_float(y));
}

// ---- DPP wave reductions (VALU pipe). Result valid in lane 63. ----
__device__ __forceinline__ float dpp_sum63(float x){
    int v;
    v = __builtin_amdgcn_update_dpp(0, __float_as_int(x), 0x111, 0xf, 0xf, true); x += __int_as_float(v);
    v = __builtin_amdgcn_update_dpp(0, __float_as_int(x), 0x112, 0xf, 0xf, true); x += __int_as_float(v);
    v = __builtin_amdgcn_update_dpp(0, __float_as_int(x), 0x114, 0xf, 0xf, true); x += __int_as_float(v);
    v = __builtin_amdgcn_update_dpp(0, __float_as_int(x), 0x118, 0xf, 0xf, true); x += __int_as_float(v);
    v = __builtin_amdgcn_update_dpp(0, __float_as_int(x), 0x142, 0xa, 0xf, true); x += __int_as_float(v);
    v = __builtin_amdgcn_update_dpp(0, __float_as_int(x), 0x143, 0xc, 0xf, true); x += __int_as_float(v);
    return x;
}
__device__ __forceinline__ float dpp_max63(float x){   // operands >= 0
    int v;
    v = __builtin_amdgcn_update_dpp(0, __float_as_int(x), 0x111, 0xf, 0xf, true); x = fmaxf(x, __int_as_float(v));
    v = __builtin_amdgcn_update_dpp(0, __float_as_int(x), 0x112, 0xf, 0xf, true); x = fmaxf(x, __int_as_float(v));
    v = __builtin_amdgcn_update_dpp(0, __float_as_int(x), 0x114, 0xf, 0xf, true); x = fmaxf(x, __int_as_float(v));
    v = __builtin_amdgcn_update_dpp(0, __float_as_int(x), 0x118, 0xf, 0xf, true); x = fmaxf(x, __int_as_float(v));
    v = __builtin_amdgcn_update_dpp(0, __float_as_int(x), 0x142, 0xa, 0xf, true); x = fmaxf(x, __int_as_float(v));
    v = __builtin_amdgcn_update_dpp(0, __float_as_int(x), 0x143, 0xc, 0xf, true); x = fmaxf(x, __int_as_float(v));
    return x;
}
__device__ __forceinline__ unsigned dpp_umax63(unsigned x){
    int v; unsigned y;
    v = __builtin_amdgcn_update_dpp(0, (int)x, 0x111, 0xf, 0xf, true); y = (unsigned)v; x = x > y ? x : y;
    v = __builtin_amdgcn_update_dpp(0, (int)x, 0x112, 0xf, 0xf, true); y = (unsigned)v; x = x > y ? x : y;
    v = __builtin_amdgcn_update_dpp(0, (int)x, 0x114, 0xf, 0xf, true); y = (unsigned)v; x = x > y ? x : y;
    v = __builtin_amdgcn_update_dpp(0, (int)x, 0x118, 0xf, 0xf, true); y = (unsigned)v; x = x > y ? x : y;
    v = __builtin_amdgcn_update_dpp(0, (int)x, 0x142, 0xa, 0xf, true); y = (unsigned)v; x = x > y ? x : y;
    v = __builtin_amdgcn_update_dpp(0, (int)x, 0x143, 0xc, 0xf, true); y = (unsigned)v; x = x > y ? x : y;
    return x;
}
__device__ __forceinline__ float bcast63f(float x){
    return __int_as_float(__builtin_amdgcn_readlane(__float_as_int(x), 63));
}
__device__ __forceinline__ unsigned bcast63u(unsigned x){
    return (unsigned)__builtin_amdgcn_readlane((int)x, 63);
}

// exp(-i*pi*r/512), r = 0..7 (compile-time literals after unroll)
__device__ __forceinline__ float2 rotc(int r){
    const float C[8] = {1.0f, 0.99998117528f, 0.99992470184f, 0.99983058180f,
                        0.99969881870f, 0.99952941750f, 0.99932238459f, 0.99907772775f};
    const float S[8] = {0.0f, 0.00613588465f, 0.01227153829f, 0.01840672991f,
                        0.02454122852f, 0.03067480318f, 0.03680722294f, 0.04293825693f};
    return make_float2(C[r], -S[r]);
}

__device__ __forceinline__ float psd_combine(float2 z, float2 zr, float2 uw){
    float Ex = 0.5f * (z.x + zr.x);
    float Ey = 0.5f * (z.y - zr.y);
    float Ox = 0.5f * (z.y + zr.y);
    float Oy = -0.5f * (z.x - zr.x);
    float Xx = Ex + uw.x * Ox - uw.y * Oy;
    float Xy = Ey + uw.x * Oy + uw.y * Ox;
    return Xx * Xx + Xy * Xy;
}

// 8-point DIT FFT in registers, natural-order output
__device__ __forceinline__ void fft8(float2* z){
    float2 c0 = cadd2(z[0], z[4]), c1 = csub2(z[0], z[4]);
    float2 c2 = cadd2(z[2], z[6]), c3 = csub2(z[2], z[6]);
    float2 c4 = cadd2(z[1], z[5]), c5 = csub2(z[1], z[5]);
    float2 c6 = cadd2(z[3], z[7]), c7 = csub2(z[3], z[7]);
    float2 mi3 = make_float2(c3.y, -c3.x);
    float2 mi7 = make_float2(c7.y, -c7.x);
    float2 d0 = cadd2(c0, c2), d2 = csub2(c0, c2);
    float2 d1 = cadd2(c1, mi3), d3 = csub2(c1, mi3);
    float2 d4 = cadd2(c4, c6), d6 = csub2(c4, c6);
    float2 d5 = cadd2(c5, mi7), d7 = csub2(c5, mi7);
    const float S2 = 0.70710678118654752f;
    float2 w1d5 = make_float2(S2 * (d5.x + d5.y), S2 * (d5.y - d5.x));
    float2 mid6 = make_float2(d6.y, -d6.x);
    float2 w3d7 = make_float2(S2 * (d7.y - d7.x), -S2 * (d7.x + d7.y));
    z[0] = cadd2(d0, d4);  z[4] = csub2(d0, d4);
    z[1] = cadd2(d1, w1d5); z[5] = csub2(d1, w1d5);
    z[2] = cadd2(d2, mid6); z[6] = csub2(d2, mid6);
    z[3] = cadd2(d3, w3d7); z[7] = csub2(d3, w3d7);
}

// ---------------- Kernel 1: wave-per-2-rows register FFT + PSD + stats ----------------
// NOTE: no second __launch_bounds__ arg — on this toolchain it maps to a VGPR
// budget of ~256/W and forced catastrophic scratch spills (R3: W=8 -> 32 VGPR,
// R5: W=4 -> 64 VGPR). Natural allocation (~120 VGPR) -> 4 waves/SIMD.
__global__ __launch_bounds__(256)
void k1(const float* __restrict__ preds, const int* __restrict__ FsPtr,
        float* __restrict__ gpsd, float* __restrict__ gband, float* __restrict__ gsparse,
        int B, int npair)
{
    const int tid  = threadIdx.x;
    const int lane = tid & 63;
    const int wid  = tid >> 6;
    const int Fs   = *FsPtr;

    // band parameters (uniform grid => argmin == rint(target/step))
    const double stepd = (double)Fs * 0.5 / (double)(NF - 1);
    const int left  = (int)rint((40.0 / 60.0) / stepd);
    const int right = (int)rint((180.0 / 60.0) / stepd);
    const double binw = (double)Fs * 0.5 / (double)NF;
    int delta = (int)rint((6.0 / 60.0) / binw);
    if (delta < 1) delta = 1;

    const int K  = brev6(lane);
    const int kk = K << 3;
    const float PIF = 3.14159265358979323846f;

    // twiddle tables (registers)
    float2 tw2[8];                        // W_512^{lane*r}, r=1..7
    #pragma unroll
    for (int r = 1; r < 8; ++r) {
        float s, c;
        sincosf(-2.0f * PIF * (float)(lane * r) / 512.0f, &s, &c);
        tw2[r] = make_float2(c, s);
    }
    float2 wS[6];                         // hi lanes: W_{2m}^{lane&(m-1)}, lo: (1,0)
    #pragma unroll
    for (int s = 0; s < 6; ++s) {
        const int m = 32 >> s;
        if (lane & m) {
            float sn, cs;
            sincosf(-2.0f * PIF * (float)(lane & (m - 1)) / (float)(2 * m), &sn, &cs);
            wS[s] = make_float2(cs, sn);
        } else {
            wS[s] = make_float2(1.f, 0.f);
        }
    }
    float2 uw0;
    { float s, c; sincosf(-PIF * (float)K / 64.0f, &s, &c); uw0 = make_float2(c, s); }
    const int p0idx = brev6((64 - K) & 63);

    float baccR[8] = {0.f,0.f,0.f,0.f,0.f,0.f,0.f,0.f};
    float bacc512 = 0.f;
    float accB = 0.f, accS = 0.f;

    const int gw   = blockIdx.x * 4 + wid;
    const int row0base = gw * (2 * npair);

    for (int pp = 0; pp < npair; ++pp) {
        const int rowA = row0base + 2 * pp;
        if (rowA >= B) break;
        const int rowB = rowA + 1;
        const float valB = (rowB < B) ? 1.f : 0.f;
        const int rowBc = (rowB < B) ? rowB : rowA;

        // ---- load both rows (coalesced 8B/lane) ----
        const float2* srcA = (const float2*)(preds + (size_t)rowA * NFFT);
        const float2* srcB = (const float2*)(preds + (size_t)rowBc * NFFT);
        float2 zA[8], zB[8];
        #pragma unroll
        for (int r = 0; r < 8; ++r) { zA[r] = srcA[(r << 6) + lane]; zB[r] = srcB[(r << 6) + lane]; }

        // ---- step 1: 8-point FFT (both rows) ----
        fft8(zA);
        fft8(zB);

        // ---- step 2: twiddle W_512^{lane*r} ----
        #pragma unroll
        for (int r = 1; r < 8; ++r) { zA[r] = cmul2(zA[r], tw2[r]); zB[r] = cmul2(zB[r], tw2[r]); }

        // ---- step 3: 64-point DIF across lanes, both rows interleaved ----
        #pragma unroll
        for (int s = 0; s < 6; ++s) {
            const int m = 32 >> s;
            const float sg = (lane & m) ? -1.f : 1.f;
            const float2 w = wS[s];
            #pragma unroll
            for (int r = 0; r < 8; ++r) {
                float2 pA, pB;
                if (m >= 4)      { pA = shflxor2(zA[r], m);    pB = shflxor2(zB[r], m); }
                else if (m == 2) { pA = dppqp2<0x4E>(zA[r]);   pB = dppqp2<0x4E>(zB[r]); }
                else             { pA = dppqp2<0xB1>(zA[r]);   pB = dppqp2<0xB1>(zB[r]); }
                // lo: (z+p)*1 ; hi: (p-z)*wS  -> inner = p + sg*z, then *w
                float2 iA = make_float2(fmaf(sg, zA[r].x, pA.x), fmaf(sg, zA[r].y, pA.y));
                float2 iB = make_float2(fmaf(sg, zB[r].x, pB.x), fmaf(sg, zB[r].y, pB.y));
                zA[r] = cmul2(iA, w);
                zB[r] = cmul2(iB, w);
            }
        }
        // lane holds Z[kk + r] for each row

        float p512A = 0.f, p512B = 0.f;
        if (lane == 0) {
            float qA = zA[0].x - zA[0].y; p512A = qA * qA;
            float qB = zB[0].x - zB[0].y; p512B = qB * qB;
        }

        // ---- real-unpack + PSD (both rows) ----
        float PA[8], PB[8];
        {
            float2 zrA = shflidx2(zA[0], p0idx);
            float2 zrB = shflidx2(zB[0], p0idx);
            PA[0] = psd_combine(zA[0], zrA, uw0);
            PB[0] = psd_combine(zB[0], zrB, uw0);
        }
        #pragma unroll
        for (int r = 1; r < 8; ++r) {
            float2 uwr = cmul2(uw0, rotc(r));
            float2 zrA = shflxor2(zA[8 - r], 63);
            float2 zrB = shflxor2(zB[8 - r], 63);
            PA[r] = psd_combine(zA[r], zrA, uwr);
            PB[r] = psd_combine(zB[r], zrB, uwr);
        }

        // ---- stats (both rows, DPP reductions) ----
        float tpA = p512A, ipA = 0.f, mvA = 0.f;
        float tpB = p512B, ipB = 0.f, mvB = 0.f;
        #pragma unroll
        for (int r = 0; r < 8; ++r) {
            const int k = kk + r;
            tpA += PA[r]; tpB += PB[r];
            if (k >= left && k < right) {
                ipA += PA[r]; mvA = fmaxf(mvA, PA[r]);
                ipB += PB[r]; mvB = fmaxf(mvB, PB[r]);
            }
        }
        const float tpSA = dpp_sum63(tpA), tpSB = dpp_sum63(tpB);
        const float ipSA = dpp_sum63(ipA), ipSB = dpp_sum63(ipB);
        const float mxA = bcast63f(dpp_max63(mvA));
        const float mxB = bcast63f(dpp_max63(mvB));

        unsigned candA = 0u, candB = 0u;
        #pragma unroll
        for (int r = 0; r < 8; ++r) {
            const int k = kk + r;
            if (k >= left && k < right) {
                if (PA[r] == mxA) { unsigned c = ~(unsigned)k; candA = candA > c ? candA : c; }
                if (PB[r] == mxB) { unsigned c = ~(unsigned)k; candB = candB > c ? candB : c; }
            }
        }
        const int peakA = (int)(~bcast63u(dpp_umax63(candA)));
        const int peakB = (int)(~bcast63u(dpp_umax63(candB)));
        const int loA = max(left, peakA - delta), hiA = min(right, peakA + delta);
        const int loB = max(left, peakB - delta), hiB = min(right, peakB + delta);
        float nsA = 0.f, nsB = 0.f;
        #pragma unroll
        for (int r = 0; r < 8; ++r) {
            const int k = kk + r;
            if (k >= loA && k < hiA) nsA += PA[r];
            if (k >= loB && k < hiB) nsB += PB[r];
        }
        const float nsSA = dpp_sum63(nsA), nsSB = dpp_sum63(nsB);

        const float eps = 1e-8f * (float)(right - left);
        accB += (tpSA - ipSA) / (1e-8f + tpSA) + valB * ((tpSB - ipSB) / (1e-8f + tpSB));
        accS += (ipSA - nsSA) / (ipSA + eps)   + valB * ((ipSB - nsSB) / (ipSB + eps));

        #pragma unroll
        for (int r = 0; r < 8; ++r) baccR[r] += PA[r] + valB * PB[r];
        bacc512 += p512A + valB * p512B;
    }

    // ---- per-wave flush straight to global atomics ----
    #pragma unroll
    for (int r = 0; r < 8; ++r) atomicAdd(&gpsd[kk + r], baccR[r]);
    if (lane == 0)  atomicAdd(&gpsd[512], bacc512);
    if (lane == 63) { atomicAdd(gband, accB); atomicAdd(gsparse, accS); }
}

// ---------------- Kernel 2: variance loss + final combine ----------------
__global__ __launch_bounds__(256)
void k2(const float* __restrict__ gpsd, const float* __restrict__ gband,
        const float* __restrict__ gsparse, const int* __restrict__ FsPtr,
        float* __restrict__ out, int B)
{
    __shared__ float a[NF];
    __shared__ float b[NF];
    __shared__ float red[4];

    const int tid = threadIdx.x;
    const int Fs  = *FsPtr;

    a[tid] = gpsd[tid]; a[tid + 256] = gpsd[tid + 256];
    if (tid == 0) a[512] = gpsd[512];
    __syncthreads();

    float sp = a[tid] + a[tid + 256] + (tid == 0 ? a[512] : 0.f);
    #pragma unroll
    for (int off = 32; off > 0; off >>= 1) sp += __shfl_down(sp, off);
    const int wid = tid >> 6, lane = tid & 63;
    if (lane == 0) red[wid] = sp;
    __syncthreads();
    const float S = red[0] + red[1] + red[2] + red[3];
    const float inv = 1.f / (1e-8f + S);
    a[tid] *= inv; a[tid + 256] *= inv;
    if (tid == 0) a[512] *= inv;
    __syncthreads();

    float* pa = a; float* pb = b;
    for (int off = 1; off < NF; off <<= 1) {
        for (int i = tid; i < NF; i += 256)
            pb[i] = pa[i] + (i >= off ? pa[i - off] : 0.f);
        __syncthreads();
        float* t = pa; pa = pb; pb = t;
    }

    const double fs2 = (double)Fs * 0.5;
    const double stp = fs2 / (double)(NF - 1);
    float vp = 0.f;
    for (int i = tid; i < NF; i += 256) {
        float Q = fminf(fmaxf(pa[i], 0.f), 1.f);
        float P = (float)((double)i * stp) / (float)fs2;
        P = fminf(fmaxf(P, 0.f), 1.f);
        const float d = P - Q;
        vp += d * d;
    }
    #pragma unroll
    for (int off = 32; off > 0; off >>= 1) vp += __shfl_down(vp, off);
    if (lane == 0) red[wid] = vp;
    __syncthreads();
    if (tid == 0) {
        const float var = (red[0] + red[1] + red[2] + red[3]) / (float)NF;
        out[0] = (*gband) / (float)B + (*gsparse) / (float)B + var;
    }
}

extern "C" void kernel_launch(void* const* d_in, const int* in_sizes, int n_in,
                              void* d_out, int out_size, void* d_ws, size_t ws_size,
                              hipStream_t stream)
{
    const float* preds = (const float*)d_in[0];
    const int*   Fs    = (const int*)d_in[1];
    const int B = in_sizes[0] / NFFT;

    float* gpsd    = (float*)d_ws;
    float* gband   = gpsd + NF;
    float* gsparse = gband + 1;

    (void)hipMemsetAsync(d_ws, 0, (NF + 2) * sizeof(float), stream);

    const int npair = 2;                      // 4 rows per wave
    const int rowsPerWave = 2 * npair;
    const int nwaves = (B + rowsPerWave - 1) / rowsPerWave;
    const int nblk   = (nwaves + 3) / 4;

    hipLaunchKernelGGL(k1, dim3(nblk), dim3(256), 0, stream,
                       preds, Fs, gpsd, gband, gsparse, B, npair);
    hipLaunchKernelGGL(k2, dim3(1), dim3(256), 0, stream,
                       gpsd, gband, gsparse, Fs, (float*)d_out, B);
}

// Round 7
// 70.468 us; speedup vs baseline: 23.3737x; 11.5982x over previous
//
#include <hip/hip_runtime.h>
#include <math.h>

#define NFFT 1024
#define NF   513   // NFFT/2 + 1

__device__ __forceinline__ float2 cadd2(float2 a, float2 b){ return make_float2(a.x+b.x, a.y+b.y); }
__device__ __forceinline__ float2 csub2(float2 a, float2 b){ return make_float2(a.x-b.x, a.y-b.y); }
__device__ __forceinline__ float2 cmul2(float2 a, float2 b){ return make_float2(a.x*b.x - a.y*b.y, a.x*b.y + a.y*b.x); }

__device__ __forceinline__ float2 shflxor2(float2 v, int m){
    return make_float2(__shfl_xor(v.x, m), __shfl_xor(v.y, m));
}
__device__ __forceinline__ float2 shflidx2(float2 v, int idx){
    return make_float2(__shfl(v.x, idx), __shfl(v.y, idx));
}
__device__ __forceinline__ int brev6(int x){ return (int)(__brev((unsigned)x) >> 26); }

// DPP quad_perm: xor1 = [1,0,3,2] = 0xB1, xor2 = [2,3,0,1] = 0x4E
template<int CTRL>
__device__ __forceinline__ float2 dppqp2(float2 v){
    int x = __builtin_amdgcn_update_dpp(0, __float_as_int(v.x), CTRL, 0xf, 0xf, true);
    int y = __builtin_amdgcn_update_dpp(0, __float_as_int(v.y), CTRL, 0xf, 0xf, true);
    return make_float2(__int_as_float(x), __int_as_float(y));
}

// ---- DPP wave reductions (VALU pipe). Result valid in lane 63. ----
__device__ __forceinline__ float dpp_sum63(float x){
    int v;
    v = __builtin_amdgcn_update_dpp(0, __float_as_int(x), 0x111, 0xf, 0xf, true); x += __int_as_float(v);
    v = __builtin_amdgcn_update_dpp(0, __float_as_int(x), 0x112, 0xf, 0xf, true); x += __int_as_float(v);
    v = __builtin_amdgcn_update_dpp(0, __float_as_int(x), 0x114, 0xf, 0xf, true); x += __int_as_float(v);
    v = __builtin_amdgcn_update_dpp(0, __float_as_int(x), 0x118, 0xf, 0xf, true); x += __int_as_float(v);
    v = __builtin_amdgcn_update_dpp(0, __float_as_int(x), 0x142, 0xa, 0xf, true); x += __int_as_float(v);
    v = __builtin_amdgcn_update_dpp(0, __float_as_int(x), 0x143, 0xc, 0xf, true); x += __int_as_float(v);
    return x;
}
__device__ __forceinline__ float dpp_max63(float x){   // operands >= 0
    int v;
    v = __builtin_amdgcn_update_dpp(0, __float_as_int(x), 0x111, 0xf, 0xf, true); x = fmaxf(x, __int_as_float(v));
    v = __builtin_amdgcn_update_dpp(0, __float_as_int(x), 0x112, 0xf, 0xf, true); x = fmaxf(x, __int_as_float(v));
    v = __builtin_amdgcn_update_dpp(0, __float_as_int(x), 0x114, 0xf, 0xf, true); x = fmaxf(x, __int_as_float(v));
    v = __builtin_amdgcn_update_dpp(0, __float_as_int(x), 0x118, 0xf, 0xf, true); x = fmaxf(x, __int_as_float(v));
    v = __builtin_amdgcn_update_dpp(0, __float_as_int(x), 0x142, 0xa, 0xf, true); x = fmaxf(x, __int_as_float(v));
    v = __builtin_amdgcn_update_dpp(0, __float_as_int(x), 0x143, 0xc, 0xf, true); x = fmaxf(x, __int_as_float(v));
    return x;
}
__device__ __forceinline__ unsigned dpp_umax63(unsigned x){
    int v; unsigned y;
    v = __builtin_amdgcn_update_dpp(0, (int)x, 0x111, 0xf, 0xf, true); y = (unsigned)v; x = x > y ? x : y;
    v = __builtin_amdgcn_update_dpp(0, (int)x, 0x112, 0xf, 0xf, true); y = (unsigned)v; x = x > y ? x : y;
    v = __builtin_amdgcn_update_dpp(0, (int)x, 0x114, 0xf, 0xf, true); y = (unsigned)v; x = x > y ? x : y;
    v = __builtin_amdgcn_update_dpp(0, (int)x, 0x118, 0xf, 0xf, true); y = (unsigned)v; x = x > y ? x : y;
    v = __builtin_amdgcn_update_dpp(0, (int)x, 0x142, 0xa, 0xf, true); y = (unsigned)v; x = x > y ? x : y;
    v = __builtin_amdgcn_update_dpp(0, (int)x, 0x143, 0xc, 0xf, true); y = (unsigned)v; x = x > y ? x : y;
    return x;
}
__device__ __forceinline__ float bcast63f(float x){
    return __int_as_float(__builtin_amdgcn_readlane(__float_as_int(x), 63));
}
__device__ __forceinline__ unsigned bcast63u(unsigned x){
    return (unsigned)__builtin_amdgcn_readlane((int)x, 63);
}

// exp(-i*pi*r/512), r = 0..7 (compile-time literals after unroll)
__device__ __forceinline__ float2 rotc(int r){
    const float C[8] = {1.0f, 0.99998117528f, 0.99992470184f, 0.99983058180f,
                        0.99969881870f, 0.99952941750f, 0.99932238459f, 0.99907772775f};
    const float S[8] = {0.0f, 0.00613588465f, 0.01227153829f, 0.01840672991f,
                        0.02454122852f, 0.03067480318f, 0.03680722294f, 0.04293825693f};
    return make_float2(C[r], -S[r]);
}

__device__ __forceinline__ float psd_combine(float2 z, float2 zr, float2 uw){
    float Ex = 0.5f * (z.x + zr.x);
    float Ey = 0.5f * (z.y - zr.y);
    float Ox = 0.5f * (z.y + zr.y);
    float Oy = -0.5f * (z.x - zr.x);
    float Xx = Ex + uw.x * Ox - uw.y * Oy;
    float Xy = Ey + uw.x * Oy + uw.y * Ox;
    return Xx * Xx + Xy * Xy;
}

// 8-point DIT FFT in registers, natural-order output
__device__ __forceinline__ void fft8(float2* z){
    float2 c0 = cadd2(z[0], z[4]), c1 = csub2(z[0], z[4]);
    float2 c2 = cadd2(z[2], z[6]), c3 = csub2(z[2], z[6]);
    float2 c4 = cadd2(z[1], z[5]), c5 = csub2(z[1], z[5]);
    float2 c6 = cadd2(z[3], z[7]), c7 = csub2(z[3], z[7]);
    float2 mi3 = make_float2(c3.y, -c3.x);
    float2 mi7 = make_float2(c7.y, -c7.x);
    float2 d0 = cadd2(c0, c2), d2 = csub2(c0, c2);
    float2 d1 = cadd2(c1, mi3), d3 = csub2(c1, mi3);
    float2 d4 = cadd2(c4, c6), d6 = csub2(c4, c6);
    float2 d5 = cadd2(c5, mi7), d7 = csub2(c5, mi7);
    const float S2 = 0.70710678118654752f;
    float2 w1d5 = make_float2(S2 * (d5.x + d5.y), S2 * (d5.y - d5.x));
    float2 mid6 = make_float2(d6.y, -d6.x);
    float2 w3d7 = make_float2(S2 * (d7.y - d7.x), -S2 * (d7.x + d7.y));
    z[0] = cadd2(d0, d4);  z[4] = csub2(d0, d4);
    z[1] = cadd2(d1, w1d5); z[5] = csub2(d1, w1d5);
    z[2] = cadd2(d2, mid6); z[6] = csub2(d2, mid6);
    z[3] = cadd2(d3, w3d7); z[7] = csub2(d3, w3d7);
}

// ---------------- Kernel 1: wave-per-2-rows register FFT + PSD + stats ----------------
// NOTE: no second __launch_bounds__ arg — on this toolchain it maps to a VGPR
// budget of ~256/W and forced catastrophic scratch spills (R3: W=8 -> 32 VGPR,
// R5: W=4 -> 64 VGPR). Natural allocation (~110 VGPR) -> 4 waves/SIMD.
// NOTE: flush MUST be lane-consecutive coalesced atomics (R6: scattered
// per-wave atomics -> 2.1M 32B memory-side RMWs -> 807us).
__global__ __launch_bounds__(256)
void k1(const float* __restrict__ preds, const int* __restrict__ FsPtr,
        float* __restrict__ gpsd, float* __restrict__ gband, float* __restrict__ gsparse,
        int B, int npair)
{
    __shared__ float wacc[4][NF];   // per-wave PSD partials (each wave writes all 513)
    __shared__ float wscal[8];      // per-wave accB, accS

    const int tid  = threadIdx.x;
    const int lane = tid & 63;
    const int wid  = tid >> 6;
    const int Fs   = *FsPtr;

    // band parameters (uniform grid => argmin == rint(target/step))
    const double stepd = (double)Fs * 0.5 / (double)(NF - 1);
    const int left  = (int)rint((40.0 / 60.0) / stepd);
    const int right = (int)rint((180.0 / 60.0) / stepd);
    const double binw = (double)Fs * 0.5 / (double)NF;
    int delta = (int)rint((6.0 / 60.0) / binw);
    if (delta < 1) delta = 1;

    const int K  = brev6(lane);
    const int kk = K << 3;
    const float PIF = 3.14159265358979323846f;

    // twiddle tables (registers)
    float2 tw2[8];                        // W_512^{lane*r}, r=1..7
    #pragma unroll
    for (int r = 1; r < 8; ++r) {
        float s, c;
        sincosf(-2.0f * PIF * (float)(lane * r) / 512.0f, &s, &c);
        tw2[r] = make_float2(c, s);
    }
    float2 wS[6];                         // hi lanes: W_{2m}^{lane&(m-1)}, lo: (1,0)
    #pragma unroll
    for (int s = 0; s < 6; ++s) {
        const int m = 32 >> s;
        if (lane & m) {
            float sn, cs;
            sincosf(-2.0f * PIF * (float)(lane & (m - 1)) / (float)(2 * m), &sn, &cs);
            wS[s] = make_float2(cs, sn);
        } else {
            wS[s] = make_float2(1.f, 0.f);
        }
    }
    float2 uw0;
    { float s, c; sincosf(-PIF * (float)K / 64.0f, &s, &c); uw0 = make_float2(c, s); }
    const int p0idx = brev6((64 - K) & 63);

    float baccR[8] = {0.f,0.f,0.f,0.f,0.f,0.f,0.f,0.f};
    float bacc512 = 0.f;
    float accB = 0.f, accS = 0.f;

    const int gw   = blockIdx.x * 4 + wid;
    const int row0base = gw * (2 * npair);

    for (int pp = 0; pp < npair; ++pp) {
        const int rowA = row0base + 2 * pp;
        if (rowA >= B) break;
        const int rowB = rowA + 1;
        const float valB = (rowB < B) ? 1.f : 0.f;
        const int rowBc = (rowB < B) ? rowB : rowA;

        // ---- load both rows (coalesced 8B/lane) ----
        const float2* srcA = (const float2*)(preds + (size_t)rowA * NFFT);
        const float2* srcB = (const float2*)(preds + (size_t)rowBc * NFFT);
        float2 zA[8], zB[8];
        #pragma unroll
        for (int r = 0; r < 8; ++r) { zA[r] = srcA[(r << 6) + lane]; zB[r] = srcB[(r << 6) + lane]; }

        // ---- step 1: 8-point FFT (both rows) ----
        fft8(zA);
        fft8(zB);

        // ---- step 2: twiddle W_512^{lane*r} ----
        #pragma unroll
        for (int r = 1; r < 8; ++r) { zA[r] = cmul2(zA[r], tw2[r]); zB[r] = cmul2(zB[r], tw2[r]); }

        // ---- step 3: 64-point DIF across lanes, both rows interleaved ----
        #pragma unroll
        for (int s = 0; s < 6; ++s) {
            const int m = 32 >> s;
            const float sg = (lane & m) ? -1.f : 1.f;
            const float2 w = wS[s];
            #pragma unroll
            for (int r = 0; r < 8; ++r) {
                float2 pA, pB;
                if (m >= 4)      { pA = shflxor2(zA[r], m);    pB = shflxor2(zB[r], m); }
                else if (m == 2) { pA = dppqp2<0x4E>(zA[r]);   pB = dppqp2<0x4E>(zB[r]); }
                else             { pA = dppqp2<0xB1>(zA[r]);   pB = dppqp2<0xB1>(zB[r]); }
                // lo: (z+p)*1 ; hi: (p-z)*wS  -> inner = p + sg*z, then *w
                float2 iA = make_float2(fmaf(sg, zA[r].x, pA.x), fmaf(sg, zA[r].y, pA.y));
                float2 iB = make_float2(fmaf(sg, zB[r].x, pB.x), fmaf(sg, zB[r].y, pB.y));
                zA[r] = cmul2(iA, w);
                zB[r] = cmul2(iB, w);
            }
        }
        // lane holds Z[kk + r] for each row

        float p512A = 0.f, p512B = 0.f;
        if (lane == 0) {
            float qA = zA[0].x - zA[0].y; p512A = qA * qA;
            float qB = zB[0].x - zB[0].y; p512B = qB * qB;
        }

        // ---- real-unpack + PSD (both rows) ----
        float PA[8], PB[8];
        {
            float2 zrA = shflidx2(zA[0], p0idx);
            float2 zrB = shflidx2(zB[0], p0idx);
            PA[0] = psd_combine(zA[0], zrA, uw0);
            PB[0] = psd_combine(zB[0], zrB, uw0);
        }
        #pragma unroll
        for (int r = 1; r < 8; ++r) {
            float2 uwr = cmul2(uw0, rotc(r));
            float2 zrA = shflxor2(zA[8 - r], 63);
            float2 zrB = shflxor2(zB[8 - r], 63);
            PA[r] = psd_combine(zA[r], zrA, uwr);
            PB[r] = psd_combine(zB[r], zrB, uwr);
        }

        // ---- stats (both rows, DPP reductions) ----
        float tpA = p512A, ipA = 0.f, mvA = 0.f;
        float tpB = p512B, ipB = 0.f, mvB = 0.f;
        #pragma unroll
        for (int r = 0; r < 8; ++r) {
            const int k = kk + r;
            tpA += PA[r]; tpB += PB[r];
            if (k >= left && k < right) {
                ipA += PA[r]; mvA = fmaxf(mvA, PA[r]);
                ipB += PB[r]; mvB = fmaxf(mvB, PB[r]);
            }
        }
        const float tpSA = dpp_sum63(tpA), tpSB = dpp_sum63(tpB);
        const float ipSA = dpp_sum63(ipA), ipSB = dpp_sum63(ipB);
        const float mxA = bcast63f(dpp_max63(mvA));
        const float mxB = bcast63f(dpp_max63(mvB));

        unsigned candA = 0u, candB = 0u;
        #pragma unroll
        for (int r = 0; r < 8; ++r) {
            const int k = kk + r;
            if (k >= left && k < right) {
                if (PA[r] == mxA) { unsigned c = ~(unsigned)k; candA = candA > c ? candA : c; }
                if (PB[r] == mxB) { unsigned c = ~(unsigned)k; candB = candB > c ? candB : c; }
            }
        }
        const int peakA = (int)(~bcast63u(dpp_umax63(candA)));
        const int peakB = (int)(~bcast63u(dpp_umax63(candB)));
        const int loA = max(left, peakA - delta), hiA = min(right, peakA + delta);
        const int loB = max(left, peakB - delta), hiB = min(right, peakB + delta);
        float nsA = 0.f, nsB = 0.f;
        #pragma unroll
        for (int r = 0; r < 8; ++r) {
            const int k = kk + r;
            if (k >= loA && k < hiA) nsA += PA[r];
            if (k >= loB && k < hiB) nsB += PB[r];
        }
        const float nsSA = dpp_sum63(nsA), nsSB = dpp_sum63(nsB);

        const float eps = 1e-8f * (float)(right - left);
        accB += (tpSA - ipSA) / (1e-8f + tpSA) + valB * ((tpSB - ipSB) / (1e-8f + tpSB));
        accS += (ipSA - nsSA) / (ipSA + eps)   + valB * ((ipSB - nsSB) / (ipSB + eps));

        #pragma unroll
        for (int r = 0; r < 8; ++r) baccR[r] += PA[r] + valB * PB[r];
        bacc512 += p512A + valB * p512B;
    }

    // ---- stage per-wave partials in LDS (non-atomic; each wave owns a row) ----
    #pragma unroll
    for (int r = 0; r < 8; ++r) wacc[wid][kk + r] = baccR[r];
    if (lane == 0)  wacc[wid][512] = bacc512;
    if (lane == 63) { wscal[wid] = accB; wscal[4 + wid] = accS; }
    __syncthreads();

    // ---- block flush: lane-consecutive coalesced global atomics ----
    {
        float s0 = wacc[0][tid] + wacc[1][tid] + wacc[2][tid] + wacc[3][tid];
        atomicAdd(&gpsd[tid], s0);
        float s1 = wacc[0][tid + 256] + wacc[1][tid + 256] + wacc[2][tid + 256] + wacc[3][tid + 256];
        atomicAdd(&gpsd[tid + 256], s1);
        if (tid == 0) {
            atomicAdd(&gpsd[512], wacc[0][512] + wacc[1][512] + wacc[2][512] + wacc[3][512]);
            atomicAdd(gband,   wscal[0] + wscal[1] + wscal[2] + wscal[3]);
            atomicAdd(gsparse, wscal[4] + wscal[5] + wscal[6] + wscal[7]);
        }
    }
}

// ---------------- Kernel 2: variance loss + final combine ----------------
__global__ __launch_bounds__(256)
void k2(const float* __restrict__ gpsd, const float* __restrict__ gband,
        const float* __restrict__ gsparse, const int* __restrict__ FsPtr,
        float* __restrict__ out, int B)
{
    __shared__ float a[NF];
    __shared__ float b[NF];
    __shared__ float red[4];

    const int tid = threadIdx.x;
    const int Fs  = *FsPtr;

    a[tid] = gpsd[tid]; a[tid + 256] = gpsd[tid + 256];
    if (tid == 0) a[512] = gpsd[512];
    __syncthreads();

    float sp = a[tid] + a[tid + 256] + (tid == 0 ? a[512] : 0.f);
    #pragma unroll
    for (int off = 32; off > 0; off >>= 1) sp += __shfl_down(sp, off);
    const int wid = tid >> 6, lane = tid & 63;
    if (lane == 0) red[wid] = sp;
    __syncthreads();
    const float S = red[0] + red[1] + red[2] + red[3];
    const float inv = 1.f / (1e-8f + S);
    a[tid] *= inv; a[tid + 256] *= inv;
    if (tid == 0) a[512] *= inv;
    __syncthreads();

    float* pa = a; float* pb = b;
    for (int off = 1; off < NF; off <<= 1) {
        for (int i = tid; i < NF; i += 256)
            pb[i] = pa[i] + (i >= off ? pa[i - off] : 0.f);
        __syncthreads();
        float* t = pa; pa = pb; pb = t;
    }

    const double fs2 = (double)Fs * 0.5;
    const double stp = fs2 / (double)(NF - 1);
    float vp = 0.f;
    for (int i = tid; i < NF; i += 256) {
        float Q = fminf(fmaxf(pa[i], 0.f), 1.f);
        float P = (float)((double)i * stp) / (float)fs2;
        P = fminf(fmaxf(P, 0.f), 1.f);
        const float d = P - Q;
        vp += d * d;
    }
    #pragma unroll
    for (int off = 32; off > 0; off >>= 1) vp += __shfl_down(vp, off);
    if (lane == 0) red[wid] = vp;
    __syncthreads();
    if (tid == 0) {
        const float var = (red[0] + red[1] + red[2] + red[3]) / (float)NF;
        out[0] = (*gband) / (float)B + (*gsparse) / (float)B + var;
    }
}

extern "C" void kernel_launch(void* const* d_in, const int* in_sizes, int n_in,
                              void* d_out, int out_size, void* d_ws, size_t ws_size,
                              hipStream_t stream)
{
    const float* preds = (const float*)d_in[0];
    const int*   Fs    = (const int*)d_in[1];
    const int B = in_sizes[0] / NFFT;

    float* gpsd    = (float*)d_ws;
    float* gband   = gpsd + NF;
    float* gsparse = gband + 1;

    (void)hipMemsetAsync(d_ws, 0, (NF + 2) * sizeof(float), stream);

    const int npair = 2;                      // 4 rows per wave
    const int rowsPerWave = 2 * npair;
    const int nwaves = (B + rowsPerWave - 1) / rowsPerWave;
    const int nblk   = (nwaves + 3) / 4;

    hipLaunchKernelGGL(k1, dim3(nblk), dim3(256), 0, stream,
                       preds, Fs, gpsd, gband, gsparse, B, npair);
    hipLaunchKernelGGL(k2, dim3(1), dim3(256), 0, stream,
                       gpsd, gband, gsparse, Fs, (float*)d_out, B);
}